// Round 4
// baseline (476.227 us; speedup 1.0000x reference)
//
#include <hip/hip_runtime.h>
#include <hip/hip_cooperative_groups.h>

namespace cg = cooperative_groups;

// Problem constants (fixed by the reference file).
#define N_NODES 8192
#define DIM     256
#define NH      64
#define DEG     32
#define G       16                 // nodes per block in phase 1
#define NBLK    (N_NODES / G)      // 512 blocks = 2 blocks/CU on 256 CUs

// ---------------------------------------------------------------------------
// FUSED PATH: single cooperative kernel, 3 phases.
//   P0: weight transpose -> WT[c4*64+t] = W[t][4c4..4c4+3]  (blocks 0..47)
//   P1: QKV projection, 16 nodes/block, 4 waves (2 node-groups x 2 split-K).
//       Q rows stay in LDS (qls) -- phase 2 of the SAME block consumes them.
//       K/V go to global (neighbors span +-416 rows, not block-local).
//   P2: attention, wave w handles nodes g0+w*4 .. g0+w*4+3 (exactly the
//       slots wave w stored in P1, so qls reads are same-wave).
// Rationale: counters (round 1) show the timed region is dominated by 2x
// ~160us 1-GiB harness re-poison fills at 85% HBM peak; the controllable
// slice is ~25-40us of kernel work + 3 launch/drain boundaries. Fusing to
// ONE launch removes 2 boundaries and the 4 MB Q global roundtrip.
// ---------------------------------------------------------------------------
__global__ __launch_bounds__(256, 2) void fused_kernel(
    const float* __restrict__ x,
    const float* __restrict__ Wq, const float* __restrict__ bq,
    const float* __restrict__ Wk, const float* __restrict__ bk,
    const float* __restrict__ Wv,
    const int* __restrict__ edge_dst,     // [E]; node i owns e = i*DEG..+DEG-1
    const int* __restrict__ edge_type,    // [E]
    const float* __restrict__ ektab,      // [NTYPES]
    float* __restrict__ Kg, float* __restrict__ Vg,   // ws: [N, NH] each
    float4* __restrict__ WT,              // ws: 3*4096 float4 (192 KB)
    float* __restrict__ out)              // [N, NH] f32
{
    cg::grid_group grid = cg::this_grid();
    const int bid = blockIdx.x;
    const int t   = threadIdx.x & 63;     // 0..63 = output dim / lane
    const int w   = threadIdx.x >> 6;     // wave id 0..3

    __shared__ float xs[G * DIM];         // 16 KB: 16 x-rows
    __shared__ float red[3][G][64];       // 12 KB: cross-wave partials by slot
    __shared__ float qls[G][64];          //  4 KB: Q rows, consumed by P2

    // ---- Phase 0: weight transpose (48 blocks x 256 thr = 12288 float4) ----
    if (bid < 48) {
        const int e   = bid * 256 + threadIdx.x;  // 0..12287
        const int mat = e >> 12;                  // /4096
        const int r   = e & 4095;                 // c4*64 + t
        const float4* src = (const float4*)(mat == 0 ? Wq : (mat == 1 ? Wk : Wv));
        WT[e] = src[(r & 63) * 64 + (r >> 6)];    // in4[t*64 + c4]
    }
    grid.sync();

    // ---- Phase 1: QKV for nodes [g0, g0+16) ----
    const int g0 = bid * G;
    {
        // Stage 16 x-rows: 4096 floats = 1024 float4; coalesced.
        const float4* xin = (const float4*)(x + (size_t)g0 * DIM);
        float4* xs4 = (float4*)xs;
        #pragma unroll
        for (int c = 0; c < (G * DIM / 4) / 256; ++c)
            xs4[threadIdx.x + 256 * c] = xin[threadIdx.x + 256 * c];
        __syncthreads();

        const int kw = w & 1;             // split-K half
        const int pr = w >> 1;            // node group: slots pr*8..pr*8+7
        const int c0 = kw * 32;           // this wave's K-half (float4 idx)
        const float4* wq = WT + c0 * 64 + t;           // coalesced loads
        const float4* wk = WT + 4096 + c0 * 64 + t;
        const float4* wv = WT + 8192 + c0 * 64 + t;
        const int s0 = pr * 8;

        float accq[8], acck[8], accv[8];
        #pragma unroll
        for (int m = 0; m < 8; ++m) { accq[m] = 0.f; acck[m] = 0.f; accv[m] = 0.f; }

        #pragma unroll 4
        for (int c = 0; c < 32; ++c) {    // 32 iterations per wave (half of K)
            const float4 aq = wq[c * 64];
            const float4 ak = wk[c * 64];
            const float4 av = wv[c * 64];
            #pragma unroll
            for (int m = 0; m < 8; ++m) {
                // wave-uniform address -> LDS broadcast, no bank conflicts
                const float4 xv = ((const float4*)(xs + (s0 + m) * DIM))[c0 + c];
                accq[m] += xv.x * aq.x + xv.y * aq.y + xv.z * aq.z + xv.w * aq.w;
                acck[m] += xv.x * ak.x + xv.y * ak.y + xv.z * ak.z + xv.w * ak.w;
                accv[m] += xv.x * av.x + xv.y * av.y + xv.z * av.z + xv.w * av.w;
            }
        }

        // Publish partials for the pair-partner wave's store slots.
        // (pr,kw) writes slots pr*8+(1-kw)*4..+4 -> 4 disjoint ranges.
        const int other0 = s0 + (1 - kw) * 4;
        #pragma unroll
        for (int m = 0; m < 4; ++m) {
            const int li = (1 - kw) * 4 + m;
            red[0][other0 + m][t] = accq[li];
            red[1][other0 + m][t] = acck[li];
            red[2][other0 + m][t] = accv[li];
        }
        __syncthreads();

        const float bqv = bq[t];
        const float bkv = bk[t];
        const int mine0 = s0 + kw * 4;    // this wave stores these 4 slots
        #pragma unroll
        for (int m = 0; m < 4; ++m) {
            const int slot = mine0 + m;
            const int li   = kw * 4 + m;
            const int o = (g0 + slot) * NH + t;   // coalesced per m
            qls[slot][t] = accq[li] + red[0][slot][t] + bqv;  // Q stays in LDS
            Kg[o] = acck[li] + red[1][slot][t] + bkv;
            Vg[o] = accv[li] + red[2][slot][t];
        }
    }
    grid.sync();   // K/V visible grid-wide; includes block barrier for qls

    // ---- Phase 2: attention. Wave w: nodes g0 + w*4 + m, m=0..3 ----
    // (these are exactly the slots THIS wave stored in P1: mine0 = w*4 when
    //  mapping (pr,kw)->w: w0->0..3, w1->4..7, w2->8..11, w3->12..15)
    #pragma unroll 1
    for (int m = 0; m < 4; ++m) {
        const int slot = w * 4 + m;
        const int i = g0 + slot;
        const float* q = qls[slot];

        float s = -1e30f;
        int nbr = 0;
        if (t < DEG) {
            const int e = i * DEG + t;
            nbr = edge_dst[e];
            const float ek = ektab[edge_type[e]];
            const float4* kr = (const float4*)(Kg + (size_t)nbr * NH);
            const float4* q4 = (const float4*)q;
            float acc = 0.f;
            #pragma unroll
            for (int d = 0; d < NH / 4; ++d) {
                const float4 kv = kr[d];
                const float4 qv = q4[d];      // uniform address -> broadcast
                acc += qv.x * kv.x + qv.y * kv.y + qv.z * kv.z + qv.w * kv.w;
            }
            s = (acc + ek) * (1.0f / 512.0f);   // /H then /sqrt(H): 64*8
        }

        // wave softmax across 64 lanes (lanes >= DEG contribute exp -> 0)
        float mx = s;
        #pragma unroll
        for (int off = 32; off > 0; off >>= 1) mx = fmaxf(mx, __shfl_xor(mx, off));
        float p = __expf(s - mx);
        float l = p;
        #pragma unroll
        for (int off = 32; off > 0; off >>= 1) l += __shfl_xor(l, off);
        p /= l;

        float o = 0.f;
        #pragma unroll 8
        for (int j = 0; j < DEG; ++j) {
            const float pj = __shfl(p, j);    // lane j holds neighbor j's prob
            const int   nj = __shfl(nbr, j);
            o += pj * Vg[(size_t)nj * NH + t];
        }

        out[i * NH + t] = o;
    }
}

// ---------------------------------------------------------------------------
// FALLBACK PATH: round-1 verified 3-kernel pipeline (363.5 us, passed).
// Used only if the cooperative launch is rejected at runtime.
// ---------------------------------------------------------------------------
__global__ __launch_bounds__(512) void transpose_w(
    const float* __restrict__ Wq, const float* __restrict__ Wk,
    const float* __restrict__ Wv, float4* __restrict__ WT)
{
    const int tid = blockIdx.x * 512 + threadIdx.x;   // 0..12287
    const int mat = tid >> 12;
    const int r   = tid & 4095;
    const float4* src = (const float4*)(mat == 0 ? Wq : (mat == 1 ? Wk : Wv));
    WT[tid] = src[(r & 63) * 64 + (r >> 6)];
}

__global__ __launch_bounds__(256) void qkv_kernel(
    const float* __restrict__ x,
    const float4* __restrict__ WTq, const float4* __restrict__ WTk,
    const float4* __restrict__ WTv,
    const float* __restrict__ bq, const float* __restrict__ bk,
    float* __restrict__ Q, float* __restrict__ K, float* __restrict__ V)
{
    const int g0 = blockIdx.x * G;
    const int t  = threadIdx.x & 63;
    const int w  = threadIdx.x >> 6;
    const int kw = w & 1;
    const int pr = w >> 1;

    __shared__ float xs[G * DIM];
    __shared__ float red[3][G][64];

    const float4* xin = (const float4*)(x + (size_t)g0 * DIM);
    float4* xs4 = (float4*)xs;
    #pragma unroll
    for (int c = 0; c < (G * DIM / 4) / 256; ++c)
        xs4[threadIdx.x + 256 * c] = xin[threadIdx.x + 256 * c];
    __syncthreads();

    const int c0 = kw * 32;
    const float4* wq = WTq + c0 * 64 + t;
    const float4* wk = WTk + c0 * 64 + t;
    const float4* wv = WTv + c0 * 64 + t;
    const int s0 = pr * 8;

    float accq[8], acck[8], accv[8];
    #pragma unroll
    for (int m = 0; m < 8; ++m) { accq[m] = 0.f; acck[m] = 0.f; accv[m] = 0.f; }

    #pragma unroll 4
    for (int c = 0; c < 32; ++c) {
        const float4 aq = wq[c * 64];
        const float4 ak = wk[c * 64];
        const float4 av = wv[c * 64];
        #pragma unroll
        for (int m = 0; m < 8; ++m) {
            const float4 xv = ((const float4*)(xs + (s0 + m) * DIM))[c0 + c];
            accq[m] += xv.x * aq.x + xv.y * aq.y + xv.z * aq.z + xv.w * aq.w;
            acck[m] += xv.x * ak.x + xv.y * ak.y + xv.z * ak.z + xv.w * ak.w;
            accv[m] += xv.x * av.x + xv.y * av.y + xv.z * av.z + xv.w * av.w;
        }
    }

    const int other0 = s0 + (1 - kw) * 4;
    #pragma unroll
    for (int m = 0; m < 4; ++m) {
        const int li = (1 - kw) * 4 + m;
        red[0][other0 + m][t] = accq[li];
        red[1][other0 + m][t] = acck[li];
        red[2][other0 + m][t] = accv[li];
    }
    __syncthreads();

    const float bqv = bq[t];
    const float bkv = bk[t];
    const int mine0 = s0 + kw * 4;
    #pragma unroll
    for (int m = 0; m < 4; ++m) {
        const int slot = mine0 + m;
        const int li   = kw * 4 + m;
        const int o = (g0 + slot) * NH + t;
        Q[o] = accq[li] + red[0][slot][t] + bqv;
        K[o] = acck[li] + red[1][slot][t] + bkv;
        V[o] = accv[li] + red[2][slot][t];
    }
}

__global__ __launch_bounds__(64) void attn_kernel(
    const float* __restrict__ Q, const float* __restrict__ K,
    const float* __restrict__ V,
    const int* __restrict__ edge_dst, const int* __restrict__ edge_type,
    const float* __restrict__ ektab, float* __restrict__ out)
{
    const int i = blockIdx.x;
    const int t = threadIdx.x;

    __shared__ float qs[NH];
    qs[t] = Q[i * NH + t];
    __syncthreads();

    float s = -1e30f;
    int nbr = 0;
    if (t < DEG) {
        const int e = i * DEG + t;
        nbr = edge_dst[e];
        const float ek = ektab[edge_type[e]];
        const float4* kr = (const float4*)(K + (size_t)nbr * NH);
        const float4* q4 = (const float4*)qs;
        float acc = 0.f;
        #pragma unroll
        for (int d = 0; d < NH / 4; ++d) {
            const float4 kv = kr[d];
            const float4 qv = q4[d];
            acc += qv.x * kv.x + qv.y * kv.y + qv.z * kv.z + qv.w * kv.w;
        }
        s = (acc + ek) * (1.0f / 512.0f);
    }

    float m = s;
    #pragma unroll
    for (int off = 32; off > 0; off >>= 1) m = fmaxf(m, __shfl_xor(m, off));
    float p = __expf(s - m);
    float l = p;
    #pragma unroll
    for (int off = 32; off > 0; off >>= 1) l += __shfl_xor(l, off);
    p /= l;

    float o = 0.f;
    #pragma unroll 8
    for (int j = 0; j < DEG; ++j) {
        const float pj = __shfl(p, j);
        const int   nj = __shfl(nbr, j);
        o += pj * V[(size_t)nj * NH + t];
    }

    out[i * NH + t] = o;
}

extern "C" void kernel_launch(void* const* d_in, const int* in_sizes, int n_in,
                              void* d_out, int out_size, void* d_ws, size_t ws_size,
                              hipStream_t stream) {
    // setup_inputs order (all floats f32 per the reference):
    // 0:x [N,D]  1:adj [N,N] (UNUSED)  2:edge_index [2,E] i32
    // 3:edge_type [E] i32  4:Wq [H,D]  5:bq [H]  6:Wk  7:bk  8:Wv
    // 9:edge_k_table [16,1]
    const float* x     = (const float*)d_in[0];
    const int*   eidx  = (const int*)d_in[2];
    const int*   etyp  = (const int*)d_in[3];
    const float* Wq    = (const float*)d_in[4];
    const float* bq    = (const float*)d_in[5];
    const float* Wk    = (const float*)d_in[6];
    const float* bk    = (const float*)d_in[7];
    const float* Wv    = (const float*)d_in[8];
    const float* ektab = (const float*)d_in[9];
    float*       out   = (float*)d_out;

    const int E = in_sizes[2] / 2;        // 262144
    const int* edge_dst = eidx + E;       // dst row of edge_index

    float*  Kg = (float*)d_ws;            // [N, NH] f32  (doubles as Q in fallback)
    float*  Vg = Kg + (size_t)N_NODES * NH;
    float*  Qf = Vg + (size_t)N_NODES * NH;             // fallback-only Q buffer
    float4* WT = (float4*)(Qf + (size_t)N_NODES * NH);  // +192 KB

    void* args[] = { (void*)&x, (void*)&Wq, (void*)&bq, (void*)&Wk, (void*)&bk,
                     (void*)&Wv, (void*)&edge_dst, (void*)&etyp,
                     (void*)&ektab, (void*)&Kg, (void*)&Vg, (void*)&WT,
                     (void*)&out };
    hipError_t err = hipLaunchCooperativeKernel((void*)fused_kernel, dim3(NBLK),
                                                dim3(256), args, 0, stream);
    if (err != hipSuccess) {
        // Verified 3-kernel fallback (round 1: passed, 363.5 us).
        transpose_w<<<dim3(24), dim3(512), 0, stream>>>(Wq, Wk, Wv, WT);
        qkv_kernel<<<dim3(NBLK), dim3(256), 0, stream>>>(
            x, WT, WT + 4096, WT + 8192, bq, bk, Qf, Kg, Vg);
        attn_kernel<<<dim3(N_NODES), dim3(64), 0, stream>>>(
            Qf, Kg, Vg, edge_dst, etyp, ektab, out);
    }
}

// Round 5
// 351.845 us; speedup vs baseline: 1.3535x; 1.3535x over previous
//
#include <hip/hip_runtime.h>

// Problem constants (fixed by the reference file).
#define N_NODES 8192
#define DIM     256
#define NH      64
#define DEG     32
#define G       8      // nodes per QKV block (8 nodes, 2 waves, split-K)

// Kernel A: QKV projection, G=8 nodes per 128-thread (2-wave) block, split-K.
// VERBATIM from the 357.7us harness-verified session-best kernel.
// Wave w covers reduction half [w*128, w*128+128) of DIM. Lane t owns output
// dim t. Cross-wave partials go through LDS indexed by ABSOLUTE node slot
// (wave w writes slots of the other wave's nodes; disjoint, no race).
// NOTE: round-1 experiment (pre-transposed coalesced weights + G=16) was
// neutral (+5.8us incl. extra launch) -> weight-load coalescing is NOT the
// binding constraint here; keep the simpler verified form.
__global__ __launch_bounds__(128) void qkv_kernel(
    const float* __restrict__ x,
    const float* __restrict__ Wq, const float* __restrict__ bq,
    const float* __restrict__ Wk, const float* __restrict__ bk,
    const float* __restrict__ Wv,
    float* __restrict__ Q, float* __restrict__ K, float* __restrict__ V)
{
    const int g0 = blockIdx.x * G;        // first node of this block
    const int t  = threadIdx.x & 63;      // 0..63 = output dim
    const int w  = threadIdx.x >> 6;      // wave id: 0 or 1

    __shared__ float xs[G * DIM];         // 8 KB: 8 x-rows
    __shared__ float red[3][G][64];       // 6 KB: cross-wave partials by node slot

    // Stage 8 x-rows: 2048 floats = 512 float4; 4 per thread, coalesced.
    const float4* xin = (const float4*)(x + (size_t)g0 * DIM);
    float4* xs4 = (float4*)xs;
    #pragma unroll
    for (int c = 0; c < (G * DIM / 4) / 128; ++c)
        xs4[threadIdx.x + 128 * c] = xin[threadIdx.x + 128 * c];
    __syncthreads();

    const int c0 = w * (DIM / 4 / 2);     // this wave's half of K-dim (float4 idx)
    const float4* wq = (const float4*)(Wq + t * DIM) + c0;
    const float4* wk = (const float4*)(Wk + t * DIM) + c0;
    const float4* wv = (const float4*)(Wv + t * DIM) + c0;

    float accq[G], acck[G], accv[G];
    #pragma unroll
    for (int m = 0; m < G; ++m) { accq[m] = 0.f; acck[m] = 0.f; accv[m] = 0.f; }

    #pragma unroll 4
    for (int c = 0; c < DIM / 4 / 2; ++c) {       // 32 iterations per wave
        const float4 aq = wq[c];
        const float4 ak = wk[c];
        const float4 av = wv[c];
        #pragma unroll
        for (int m = 0; m < G; ++m) {
            // wave-uniform address -> LDS broadcast, no bank conflicts
            const float4 xv = ((const float4*)(xs + m * DIM))[c0 + c];
            accq[m] += xv.x * aq.x + xv.y * aq.y + xv.z * aq.z + xv.w * aq.w;
            acck[m] += xv.x * ak.x + xv.y * ak.y + xv.z * ak.z + xv.w * ak.w;
            accv[m] += xv.x * av.x + xv.y * av.y + xv.z * av.z + xv.w * av.w;
        }
    }

    // Publish partials for the OTHER wave's nodes, indexed by absolute slot:
    // wave 0 writes slots 4..7, wave 1 writes slots 0..3 -> disjoint.
    const int other0 = (1 - w) * (G / 2);
    #pragma unroll
    for (int m = 0; m < G / 2; ++m) {
        red[0][other0 + m][t] = accq[other0 + m];
        red[1][other0 + m][t] = acck[other0 + m];
        red[2][other0 + m][t] = accv[other0 + m];
    }
    __syncthreads();

    const float bqv = bq[t];
    const float bkv = bk[t];
    const int mine0 = w * (G / 2);        // wave w stores nodes [w*4, w*4+4)
    #pragma unroll
    for (int m = 0; m < G / 2; ++m) {
        const int slot = mine0 + m;
        const int o = (g0 + slot) * NH + t;       // coalesced per m
        Q[o] = accq[slot] + red[0][slot][t] + bqv;
        K[o] = acck[slot] + red[1][slot][t] + bkv;
        V[o] = accv[slot] + red[2][slot][t];
    }
}

// Kernel B: sparse attention over the 32 neighbors of each node.
// v2 changes vs the 357.7us version (both target the latency-bound gathers):
//  (1) 256-thread blocks, 4 independent waves = 4 nodes/block. The old
//      __launch_bounds__(64) single-wave blocks cap at 16 workgroups/CU =
//      16 waves/CU (50% occupancy); 4-wave blocks with ~1KB LDS reach
//      32 waves/CU -> 2x latency hiding.
//  (2) QK^T uses ALL 64 lanes: lane t handles neighbor (t&31), d-half
//      (t>>5). 8 gather-loads deep instead of 16 with half the wave idle;
//      halves combined by one __shfl_xor(acc, 32). Scores are then
//      duplicated across half-waves, so softmax reductions run over
//      32-lane groups (offsets 16..1) -- each group holds every neighbor
//      exactly once, so max/sum are exact, no double-count.
__global__ __launch_bounds__(256) void attn_kernel(
    const float* __restrict__ Q, const float* __restrict__ K,
    const float* __restrict__ V,
    const int* __restrict__ edge_dst,     // [E]; node i owns e = i*DEG .. +DEG-1
    const int* __restrict__ edge_type,    // [E]
    const float* __restrict__ ektab,      // [NTYPES]
    float* __restrict__ out)              // [N, NH] f32
{
    const int w = threadIdx.x >> 6;       // wave 0..3 -> node within block
    const int t = threadIdx.x & 63;       // lane
    const int i = blockIdx.x * 4 + w;     // this wave's node

    __shared__ float qs[4][NH];           // 1 KB: one Q row per wave
    qs[w][t] = Q[i * NH + t];
    __syncthreads();                      // cross-lane LDS visibility

    // ---- scores: lane t -> neighbor jj = t&31, d-half = t>>5 ----
    const int jj   = t & 31;
    const int half = t >> 5;
    const int e    = i * DEG + jj;
    const int   nbr = edge_dst[e];        // lanes 32..63 duplicate 0..31
    const float ek  = ektab[edge_type[e]];
    const float4* kr = (const float4*)(K + (size_t)nbr * NH) + half * 8;
    const float4* q4 = (const float4*)(qs[w]) + half * 8;
    float acc = 0.f;
    #pragma unroll
    for (int d = 0; d < 8; ++d) {
        const float4 kv = kr[d];
        const float4 qv = q4[d];          // uniform address -> LDS broadcast
        acc += qv.x * kv.x + qv.y * kv.y + qv.z * kv.z + qv.w * kv.w;
    }
    acc += __shfl_xor(acc, 32);           // combine d-halves; lanes t, t^32 equal
    const float s = (acc + ek) * (1.0f / 512.0f);  // /H then /sqrt(H): 64*8

    // ---- softmax over the 32 neighbors (per 32-lane group; values are
    //      duplicated across groups so both compute the same result) ----
    float mx = s;
    #pragma unroll
    for (int off = 16; off > 0; off >>= 1) mx = fmaxf(mx, __shfl_xor(mx, off));
    float p = __expf(s - mx);
    float l = p;
    #pragma unroll
    for (int off = 16; off > 0; off >>= 1) l += __shfl_xor(l, off);
    p /= l;

    // ---- O[i][t] = sum_j p_j * V[nbr_j][t]; lane j<32 holds p_j, nbr_j ----
    float o = 0.f;
    #pragma unroll 8
    for (int j = 0; j < DEG; ++j) {
        const float pj = __shfl(p, j);
        const int   nj = __shfl(nbr, j);
        o += pj * V[(size_t)nj * NH + t];     // coalesced 256B per neighbor
    }

    out[i * NH + t] = o;
}

extern "C" void kernel_launch(void* const* d_in, const int* in_sizes, int n_in,
                              void* d_out, int out_size, void* d_ws, size_t ws_size,
                              hipStream_t stream) {
    // setup_inputs order (all floats f32 per the reference):
    // 0:x [N,D]  1:adj [N,N] (UNUSED)  2:edge_index [2,E] i32
    // 3:edge_type [E] i32  4:Wq [H,D]  5:bq [H]  6:Wk  7:bk  8:Wv
    // 9:edge_k_table [16,1]
    const float* x     = (const float*)d_in[0];
    const int*   eidx  = (const int*)d_in[2];
    const int*   etyp  = (const int*)d_in[3];
    const float* Wq    = (const float*)d_in[4];
    const float* bq    = (const float*)d_in[5];
    const float* Wk    = (const float*)d_in[6];
    const float* bk    = (const float*)d_in[7];
    const float* Wv    = (const float*)d_in[8];
    const float* ektab = (const float*)d_in[9];
    float*       out   = (float*)d_out;

    const int E = in_sizes[2] / 2;        // 262144

    float* Q = (float*)d_ws;              // [N, NH] f32
    float* K = Q + (size_t)N_NODES * NH;
    float* V = K + (size_t)N_NODES * NH;  // 6 MB of ws

    qkv_kernel<<<dim3(N_NODES / G), dim3(128), 0, stream>>>(x, Wq, bq, Wk, bk, Wv, Q, K, V);
    attn_kernel<<<dim3(N_NODES / 4), dim3(256), 0, stream>>>(Q, K, V, eidx + E, etyp, ektab, out);
}